// Round 1
// baseline (441.310 us; speedup 1.0000x reference)
//
#include <hip/hip_runtime.h>
#include <hip/hip_bf16.h>

// ConvDemodulated: B=16, C_IN=64, C_OUT=64, H=W=256.
// out[b,o,p] = clip( sum_i x[b,i,p] * wn[o,i] + bias[o], -256, 256 )
// wn[o,i] = w[o,i] * rsqrt(sum_i w[o,i]^2 + 1e-8)
//
// Memory-bound: 268 MB read + 268 MB write. Compute via bf16 MFMA so the
// matrix pipe is ~4us and the kernel is a pure streaming problem.

#define HW 65536
#define CH 64
#define BATCH_STRIDE (CH * HW)  // 4194304 elements

typedef __attribute__((ext_vector_type(8))) short short8;
typedef __attribute__((ext_vector_type(4))) float f32x4;

// --- prep: demodulate weights, store bf16 [64][64] row-major in d_ws ---
__global__ void prep_weights(const float* __restrict__ w,
                             __hip_bfloat16* __restrict__ wn) {
    int o = threadIdx.x;  // 64 threads, one per output channel
    float s = 0.f;
#pragma unroll
    for (int i = 0; i < 64; ++i) {
        float v = w[o * 64 + i];
        s += v * v;
    }
    float d = rsqrtf(s + 1e-8f);
#pragma unroll
    for (int i = 0; i < 64; ++i) {
        wn[o * 64 + i] = __float2bfloat16(w[o * 64 + i] * d);
    }
}

// --- main: each wave computes 64 output channels x 64 pixels ---
// block = 256 threads (4 waves), block tile = 256 pixels of one batch image.
// grid = 16 batches * (65536/256) ptiles = 4096 blocks.
__global__ __launch_bounds__(256) void conv1x1_mfma(
    const float* __restrict__ x, const __hip_bfloat16* __restrict__ wn,
    const float* __restrict__ bias, float* __restrict__ out) {
    const int bid = blockIdx.x;
    const int b = bid >> 8;        // 256 ptiles per batch
    const int pt = bid & 255;
    const int wv = threadIdx.x >> 6;
    const int lane = threadIdx.x & 63;
    const int r16 = lane & 15;     // pixel-in-tile (B,n) / out-channel (A,m)
    const int g = lane >> 4;       // K-group: k = g*8 + j

    const int p_wave = pt * 256 + wv * 64;   // this wave's 64-pixel strip
    const float* xb = x + (size_t)b * BATCH_STRIDE;
    float* ob = out + (size_t)b * BATCH_STRIDE;

    // A-frags: afrag[q][h] covers o-tile q (o = q*16 + r16), K-half h.
    // Lane reads 8 contiguous bf16 = 16 B from wn[o][h*32 + g*8 ..].
    short8 afrag[4][2];
#pragma unroll
    for (int q = 0; q < 4; ++q) {
#pragma unroll
        for (int h = 0; h < 2; ++h) {
            const int o = q * 16 + r16;
            const int i = h * 32 + g * 8;
            afrag[q][h] =
                *reinterpret_cast<const short8*>((const short*)wn + o * 64 + i);
        }
    }

    f32x4 acc[4][4];  // [o-tile q][pixel-tile t]
#pragma unroll
    for (int q = 0; q < 4; ++q)
#pragma unroll
        for (int t = 0; t < 4; ++t) acc[q][t] = (f32x4){0.f, 0.f, 0.f, 0.f};

#pragma unroll
    for (int t = 0; t < 4; ++t) {
        const float* xp = xb + p_wave + t * 16 + r16;
#pragma unroll
        for (int h = 0; h < 2; ++h) {
            // B-frag: lane holds x[i = h*32 + g*8 + j][p = ptile + r16], j=0..7
            short8 bfrag;
#pragma unroll
            for (int j = 0; j < 8; ++j) {
                const int i = h * 32 + g * 8 + j;
                float v = xp[(size_t)i * HW];
                __hip_bfloat16 hb = __float2bfloat16(v);
                bfrag[j] = *reinterpret_cast<short*>(&hb);
            }
#pragma unroll
            for (int q = 0; q < 4; ++q) {
                acc[q][t] = __builtin_amdgcn_mfma_f32_16x16x32_bf16(
                    afrag[q][h], bfrag, acc[q][t], 0, 0, 0);
            }
        }
    }

    // Epilogue: D lane mapping col = lane&15 (pixel), row = g*4 + reg (o).
#pragma unroll
    for (int q = 0; q < 4; ++q) {
#pragma unroll
        for (int r = 0; r < 4; ++r) {
            const int o = q * 16 + g * 4 + r;
            const float bv = bias[o];
#pragma unroll
            for (int t = 0; t < 4; ++t) {
                float v = acc[q][t][r] + bv;
                v = fminf(fmaxf(v, -256.f), 256.f);
                ob[(size_t)o * HW + p_wave + t * 16 + r16] = v;
            }
        }
    }
}

extern "C" void kernel_launch(void* const* d_in, const int* in_sizes, int n_in,
                              void* d_out, int out_size, void* d_ws,
                              size_t ws_size, hipStream_t stream) {
    const float* x = (const float*)d_in[0];
    const float* w = (const float*)d_in[1];     // [64][64][1][1]
    const float* bias = (const float*)d_in[2];  // [64]
    float* out = (float*)d_out;
    __hip_bfloat16* wn = (__hip_bfloat16*)d_ws;  // 8 KB of scratch

    prep_weights<<<1, 64, 0, stream>>>(w, wn);
    conv1x1_mfma<<<4096, 256, 0, stream>>>(x, wn, bias, out);
}